// Round 15
// baseline (778.062 us; speedup 1.0000x reference)
//
#include <hip/hip_runtime.h>
#include <cstdint>
#include <cstddef>

typedef unsigned short u16;
typedef unsigned int u32;
typedef unsigned long long u64;
typedef __attribute__((ext_vector_type(8))) short bf16x8;
typedef __attribute__((ext_vector_type(4))) float f32x4;

#define AS1 __attribute__((address_space(1)))
#define AS3 __attribute__((address_space(3)))

__device__ __forceinline__ float bf2f(u16 u){ u32 x = ((u32)u)<<16; float f; __builtin_memcpy(&f,&x,4); return f; }
__device__ __forceinline__ u16 f2bf(float f){ u32 x; __builtin_memcpy(&x,&f,4); u32 r=(x+0x7FFFu+((x>>16)&1u))>>16; return (u16)r; }

__device__ __forceinline__ float fast_sig(float x){
  return __fdividef(1.f, 1.f + __expf(-x));
}
__device__ __forceinline__ float fast_tanh(float x){
  float e = __expf(2.f*x);
  return 1.f - __fdividef(2.f, e + 1.f);
}

// device-scope stores (write-through past the producer XCD's private L2).
// REQUIRED for data produced here and consumed by blocks on other XCDs
// (feat, wout_b, flags). Plain stores strand dirty lines (R10/R11 bug).
__device__ __forceinline__ void dev_store_u16(u16* p, u16 v){
  __hip_atomic_store(p, v, __ATOMIC_RELAXED, __HIP_MEMORY_SCOPE_AGENT);
}
__device__ __forceinline__ void dev_store_u32(u32* p, u32 v){
  __hip_atomic_store(p, v, __ATOMIC_RELAXED, __HIP_MEMORY_SCOPE_AGENT);
}
__device__ __forceinline__ void dev_store_u64(u64* p, u64 v){
  __hip_atomic_store(p, v, __ATOMIC_RELAXED, __HIP_MEMORY_SCOPE_AGENT);
}

// ---------------- utility kernels ----------------

__global__ void zero_bytes(uint4* p, size_t n16){
  size_t i = (size_t)blockIdx.x*blockDim.x + threadIdx.x;
  size_t st = (size_t)gridDim.x*blockDim.x;
  uint4 z; z.x=0u; z.y=0u; z.z=0u; z.w=0u;
  for (; i<n16; i+=st) p[i]=z;
}

// gate-matrix pad+convert with wave-local (r,z,n) row permutation
__global__ void pad_convert_g(const float* __restrict__ src, int src_ld, int c0, int vcols,
                              u16* __restrict__ dst, int dcols){
  int i = blockIdx.x*256 + threadIdx.x;
  int tot = 768*dcols;
  if (i >= tot) return;
  int p = i/dcols, c = i - p*dcols;
  int wv = p/96, rem = p - wv*96, sec = rem>>5, u = rem&31;
  int j = wv*32 + u;
  float v = 0.f;
  if (j < 254 && c < vcols) v = src[(size_t)(sec*254 + j)*src_ld + c0 + c];
  dst[i] = f2bf(v);
}

// combined gi bias: b_ih + b_hh for r,z sections (permuted)
__global__ void pad_bias_comb(const float* __restrict__ ih, const float* __restrict__ hh,
                              float* __restrict__ dst){
  int p = blockIdx.x*256 + threadIdx.x;
  if (p >= 768) return;
  int wv = p/96, rem = p - wv*96, sec = rem>>5, u = rem&31;
  int j = wv*32 + u;
  float v = 0.f;
  if (j < 254){ v = ih[sec*254 + j]; if (sec < 2) v += hh[sec*254 + j]; }
  dst[p] = v;
}

__global__ void pad_bias_g(const float* __restrict__ src, float* __restrict__ dst){
  int p = blockIdx.x*256 + threadIdx.x;
  if (p >= 768) return;
  int wv = p/96, rem = p - wv*96, sec = rem>>5, u = rem&31;
  int j = wv*32 + u;
  dst[p] = (j<254) ? src[sec*254 + j] : 0.f;
}

__global__ void gather_enc(const int* __restrict__ idx, const float* __restrict__ emb, u16* __restrict__ dst){
  int i = blockIdx.x*256 + threadIdx.x;
  int r = i>>7, k = i&127;
  dst[i] = f2bf(emb[(size_t)idx[r]*128 + k]);
}

__global__ void gather_dec(const int* __restrict__ idx, const float* __restrict__ emb,
                           u16* __restrict__ dst, u16* __restrict__ feat){
  int i = blockIdx.x*256 + threadIdx.x;
  int r = i>>7, k = i&127;
  u16 v = 0;
  if (r < 3136) v = f2bf(emb[(size_t)idx[r]*128 + k]);
  dst[i] = v;
  if (r < 3136) feat[(size_t)r*640 + 508 + k] = v;   // cross-kernel: HSA release WB
}

// ------- gi GEMM (4-wave 128x128, R4 structure), bf16 OUTPUT, col bias -------

__global__ __launch_bounds__(256) void gemm_bt16(
  const u16* __restrict__ A, int lda,
  const u16* __restrict__ B, int ldb,
  u16* __restrict__ C, long long ldc,
  const float* __restrict__ bias,
  int K, int Mtiles, int Mstore)
{
  __shared__ __align__(16) u16 Abuf[2][128*64];
  __shared__ __align__(16) u16 Bbuf[2][128*64];
  const int t = threadIdx.x;
  const int w = t>>6, l = t&63;
  const int wm = w>>1, wn = w&1;
  const int mt = blockIdx.x % Mtiles, nt = blockIdx.x / Mtiles;
  const int m0 = mt<<7, n0 = nt<<7;

  const int lr = l>>3, lg = l&7;

  auto stage = [&](const u16* __restrict__ G, int ld, int base0, int k0, u16* Lbuf){
    #pragma unroll
    for (int i=0;i<4;++i){
      const int rbase = i*32 + w*8;
      const int r = rbase + lr;
      const int gsw = lg ^ (r&7);
      __builtin_amdgcn_global_load_lds(
        (const AS1 void*)(G + (size_t)(base0+r)*ld + k0 + gsw*8),
        (AS3 void*)(Lbuf + rbase*64), 16, 0, 0);
    }
  };

  f32x4 acc[4][4] = {};
  const int ksteps = K>>6;

  stage(A, lda, m0, 0, Abuf[0]);
  stage(B, ldb, n0, 0, Bbuf[0]);
  asm volatile("s_waitcnt vmcnt(0)" ::: "memory");
  __syncthreads();

  for (int ks=0; ks<ksteps; ++ks){
    const int cb = ks&1;
    if (ks+1 < ksteps){
      stage(A, lda, m0, (ks+1)<<6, Abuf[cb^1]);
      stage(B, ldb, n0, (ks+1)<<6, Bbuf[cb^1]);
    }
    const u16* Al = Abuf[cb];
    const u16* Bl = Bbuf[cb];
    #pragma unroll
    for (int kk=0;kk<2;++kk){
      const int ko = kk*32 + (l>>4)*8;
      bf16x8 af[4], bfr[4];
      #pragma unroll
      for (int m=0;m<4;++m){
        const int row = wm*64+m*16+(l&15);
        af[m] = *(const bf16x8*)&Al[row*64 + (ko ^ ((row&7)<<3))];
      }
      #pragma unroll
      for (int n=0;n<4;++n){
        const int row = wn*64+n*16+(l&15);
        bfr[n] = *(const bf16x8*)&Bl[row*64 + (ko ^ ((row&7)<<3))];
      }
      #pragma unroll
      for (int m=0;m<4;++m)
        #pragma unroll
        for (int n=0;n<4;++n)
          acc[m][n] = __builtin_amdgcn_mfma_f32_16x16x32_bf16(af[m], bfr[n], acc[m][n], 0,0,0);
    }
    asm volatile("s_waitcnt vmcnt(0)" ::: "memory");
    __syncthreads();
  }

  float bv[4];
  #pragma unroll
  for (int n=0;n<4;++n) bv[n] = bias[n0 + wn*64 + n*16 + (l&15)];
  #pragma unroll
  for (int m=0;m<4;++m){
    const int rb = m0 + wm*64 + m*16 + (l>>4)*4;
    #pragma unroll
    for (int n=0;n<4;++n){
      const int col = n0 + wn*64 + n*16 + (l&15);
      #pragma unroll
      for (int r=0;r<4;++r){
        const int rr = rb + r;
        if (rr < Mstore) C[(size_t)rr*ldc + col] = f2bf(acc[m][n][r] + bv[n]);
      }
    }
  }
}

// ---------------- FUSED scan + output-GEMM (producer-consumer) ----------------
// Blocks 0-3: GRU scan, R12 layout (gi [3200][768] bf16, COALESCED staging) +
//   LDS XOR-swizzle (32B granule, pre-swizzled per-lane global source, linear
//   LDS dest) -> conflict-free gate reads; h in registers; ctx patched into
//   dec_gi once (coalesced RMW); feat h-rows written as u64 vector dev-stores.
//   3 LDS gi buffers, 2-ahead prefetch, counted s_waitcnt + raw s_barrier.
// Blocks 4-251: W_out convert (device-scope) + gated tile consume.
// smem = max(scan 90624, gemm 98304) = 98304  <-- R14 bug: was 90624, BL overran.

__global__ __launch_bounds__(512,1) void fused_scan_gemm(
  const u16* Whhe, const u16* Whhd, const u16* Wihdc,
  const float* bhhe, const float* bhhd,
  const u16* enc_gi, u16* dec_gi,
  u16* feat, u16* wout_b, const float* W_out,
  float* Cg, const float* b_out, u32* ctr)
{
  __shared__ __align__(16) char smem[98304];
  const int t = threadIdx.x;
  const int w = t>>6, l = t&63;

  if (blockIdx.x < 4){
    // ================= scan branch =================
    const int g = blockIdx.x;
    const int la = l&15, q = l>>4;
    const int brow0 = g*16;

    u16* hb  = (u16*)smem;               // [2][16][264]  (16896 B)
    u16* gib = (u16*)(smem + 16896);     // [3][16][768]  (73728 B), XOR-swizzled

    bf16x8 Bf[48];

    auto loadW = [&](const u16* __restrict__ W){
      #pragma unroll
      for (int nt=0; nt<6; ++nt)
        #pragma unroll
        for (int kk=0; kk<8; ++kk)
          Bf[nt*8+kk] = *(const bf16x8*)&W[(size_t)(w*96 + nt*16 + la)*256 + kk*32 + q*8];
    };

    // Swizzle: logical u16 idx (b*768+col) stored at phys idx ^ (qb<<4),
    // qb=(b>>2)&3 (32B-granule XOR). Stage keeps LINEAR LDS dest (wave-uniform
    // base + lane*16B) and pre-swizzles the per-lane GLOBAL source (m173).
    size_t sinv[3];
    #pragma unroll
    for (int i=0;i<3;++i){
      const int db = i*8192 + w*1024 + l*16;       // linear dest byte
      const int b_ = db/1536;
      const int pchunk = (db - b_*1536)>>4;        // 16B chunk within row
      const int lc = pchunk ^ (((b_>>2)&3)<<1);    // logical chunk
      sinv[i] = (size_t)(brow0 + b_)*768 + lc*8;
    }
    auto stage = [&](const u16* __restrict__ gsrc, int step, u16* dstL){
      #pragma unroll
      for (int i=0;i<3;++i){
        __builtin_amdgcn_global_load_lds(
          (const AS1 void*)(gsrc + (size_t)step*49152 + sinv[i]),
          (AS3 void*)(dstL + ((i*8192 + w*1024)>>1)), 16, 0, 0);
      }
    };

    auto mm = [&](const u16* hsrc, f32x4* acc){
      #pragma unroll
      for (int kk=0; kk<8; ++kk){
        bf16x8 a = *(const bf16x8*)&hsrc[la*264 + kk*32 + q*8];
        #pragma unroll
        for (int nt=0; nt<6; ++nt)
          acc[nt] = __builtin_amdgcn_mfma_f32_16x16x32_bf16(a, Bf[nt*8+kk], acc[nt], 0,0,0);
      }
    };

    const int qsw = q<<4;   // per-lane gate-read XOR (qb == q for b=q*4+r)

    for (int i=t; i<2*16*264; i+=512) hb[i] = 0;
    loadW(Whhe);
    float bn[2];
    #pragma unroll
    for (int tl=0; tl<2; ++tl) bn[tl] = bhhe[w*96 + tl*16 + la + 64];
    float hreg[8] = {};
    stage(enc_gi, 0, gib);
    stage(enc_gi, 1, gib + 12288);
    asm volatile("s_waitcnt vmcnt(0) lgkmcnt(0)" ::: "memory");
    __builtin_amdgcn_s_barrier();

    // ---- encoder: 50 steps ----
    #pragma unroll 1
    for (int s=0; s<50; ++s){
      const int hc = s&1;
      const u16* gT = gib + (s%3)*12288;
      if (s+2 < 50) stage(enc_gi, s+2, gib + ((s+2)%3)*12288);
      f32x4 acc[6] = {};
      mm(hb + hc*4224, acc);
      #pragma unroll
      for (int tl=0; tl<2; ++tl){
        const int pr = w*96 + tl*16 + la;
        const int j  = w*32 + tl*16 + la;
        #pragma unroll
        for (int r=0;r<4;++r){
          const int b = q*4 + r;
          const int gbase = (b*768 + pr);
          const float rg = fast_sig(bf2f(gT[gbase ^ qsw])        + acc[tl][r]);
          const float zg = fast_sig(bf2f(gT[(gbase+32) ^ qsw])   + acc[2+tl][r]);
          const float ng = fast_tanh(bf2f(gT[(gbase+64) ^ qsw])  + rg*(acc[4+tl][r] + bn[tl]));
          const float h2 = (1.f-zg)*ng + zg*hreg[tl*4+r];
          hreg[tl*4+r] = h2;
          hb[(hc^1)*4224 + b*264 + j] = f2bf(h2);
        }
      }
      if (s+2 < 50) asm volatile("s_waitcnt vmcnt(3) lgkmcnt(0)" ::: "memory");
      else          asm volatile("s_waitcnt vmcnt(0) lgkmcnt(0)" ::: "memory");
      __builtin_amdgcn_s_barrier();
    }
    // context = h(50) in hb[0] and hreg

    // ---- ctx gate input (step-invariant) -> ctxb (gib[2], UNswizzled) ----
    loadW(Wihdc);
    u16* ctxb = gib + 2*12288;           // [16][768]
    {
      f32x4 acc[6] = {};
      mm(hb, acc);
      #pragma unroll
      for (int nt=0; nt<6; ++nt)
        #pragma unroll
        for (int r=0;r<4;++r)
          ctxb[(q*4+r)*768 + w*96 + nt*16 + la] = f2bf(acc[nt][r]);
    }
    asm volatile("s_waitcnt lgkmcnt(0)" ::: "memory");
    __builtin_amdgcn_s_barrier();

    // ---- patch ctx into dec_gi ONCE (coalesced 16B RMW; self-XCD only) ----
    #pragma unroll 1
    for (int idx=t; idx<49*16*96; idx+=512){
      const int row = idx/96, cch = idx - row*96;
      const int tt2 = row>>4, b = row&15;
      u16* gp = dec_gi + (size_t)(tt2*64 + brow0 + b)*768 + cch*8;
      uint4 a = *(uint4*)gp;
      const uint4 c = *(const uint4*)&ctxb[b*768 + cch*8];
      auto addbf = [](u32 x, u32 y)->u32{
        u32 lo = (u32)f2bf(bf2f((u16)(x&0xffff)) + bf2f((u16)(y&0xffff)));
        u32 hi = (u32)f2bf(bf2f((u16)(x>>16))    + bf2f((u16)(y>>16)));
        return lo | (hi<<16);
      };
      a.x=addbf(a.x,c.x); a.y=addbf(a.y,c.y); a.z=addbf(a.z,c.z); a.w=addbf(a.w,c.w);
      *(uint4*)gp = a;
    }
    asm volatile("s_waitcnt vmcnt(0)" ::: "memory");
    __builtin_amdgcn_s_barrier();

    // ---- stage decoder steps 0,1 (patched dec_gi); feat ctx cols ----
    stage(dec_gi, 0, gib);
    stage(dec_gi, 1, gib + 12288);

    #pragma unroll 1
    for (int i=t; i<49*2048; i+=512){
      const int tt = i>>11, rem = i&2047, b = rem>>7, c2 = rem&127;
      if (c2 < 127){
        u32 v = *(const u32*)&hb[b*264 + c2*2];
        dev_store_u32((u32*)&feat[(size_t)(tt*64 + brow0 + b)*640 + 254 + c2*2], v);
      }
    }

    loadW(Whhd);
    #pragma unroll
    for (int tl=0; tl<2; ++tl) bn[tl] = bhhd[w*96 + tl*16 + la + 64];
    asm volatile("s_waitcnt vmcnt(0) lgkmcnt(0)" ::: "memory");
    __builtin_amdgcn_s_barrier();

    // ---- decoder: 49 steps; feat(tt-1) written vectorized at step top ----
    #pragma unroll 1
    for (int tt=0; tt<49; ++tt){
      const int hc = tt&1;
      const u16* gT = gib + (tt%3)*12288;
      if (tt >= 1){
        #pragma unroll
        for (int i0=t; i0<1024; i0+=512){
          const int b = i0>>6, c = i0&63;
          const u16* hrow = hb + hc*4224 + b*264;
          u16* frow = feat + (size_t)((tt-1)*64 + brow0 + b)*640;
          if (c < 63) dev_store_u64((u64*)(frow + c*4), *(const u64*)(hrow + c*4));
          else        dev_store_u32((u32*)(frow + 252), *(const u32*)(hrow + 252));
        }
      }
      if (tt+2 < 49) stage(dec_gi, tt+2, gib + ((tt+2)%3)*12288);
      f32x4 acc[6] = {};
      mm(hb + hc*4224, acc);
      #pragma unroll
      for (int tl=0; tl<2; ++tl){
        const int pr = w*96 + tl*16 + la;
        const int j  = w*32 + tl*16 + la;
        #pragma unroll
        for (int r=0;r<4;++r){
          const int b = q*4 + r;
          const int gbase = (b*768 + pr);
          const float rg = fast_sig(bf2f(gT[gbase ^ qsw])        + acc[tl][r]);
          const float zg = fast_sig(bf2f(gT[(gbase+32) ^ qsw])   + acc[2+tl][r]);
          const float ng = fast_tanh(bf2f(gT[(gbase+64) ^ qsw])  + rg*(acc[4+tl][r] + bn[tl]));
          const float h2 = (1.f-zg)*ng + zg*hreg[tl*4+r];
          hreg[tl*4+r] = h2;
          hb[(hc^1)*4224 + b*264 + j] = f2bf(h2);
        }
      }
      // vmcnt(3): drains feat(tt-1) stores + stage(tt+1); stage(tt+2) in flight
      if (tt+2 < 49) asm volatile("s_waitcnt vmcnt(3) lgkmcnt(0)" ::: "memory");
      else           asm volatile("s_waitcnt vmcnt(0) lgkmcnt(0)" ::: "memory");
      __builtin_amdgcn_s_barrier();
      if (t==0) dev_store_u32(&ctr[g], (u32)tt);   // steps 0..tt-1 visible
    }
    // final: feat rows for step 48 from hb[1] (h(49))
    #pragma unroll
    for (int i0=t; i0<1024; i0+=512){
      const int b = i0>>6, c = i0&63;
      const u16* hrow = hb + 4224 + b*264;
      u16* frow = feat + (size_t)(48*64 + brow0 + b)*640;
      if (c < 63) dev_store_u64((u64*)(frow + c*4), *(const u64*)(hrow + c*4));
      else        dev_store_u32((u32*)(frow + 252), *(const u32*)(hrow + 252));
    }
    asm volatile("s_waitcnt vmcnt(0)" ::: "memory");
    __syncthreads();
    if (t==0) dev_store_u32(&ctr[g], 49u);         // all steps visible
    return;
  }

  // ================= gemm branch =================
  const int bg = blockIdx.x - 4;
  const int wm = w>>2, wn = w&3;
  const int la = l&15, q = l>>4;
  const int lr = l>>3, lg = l&7;

  u16* AL = (u16*)smem;             // [2][128*64]  (32768 B)
  u16* BL = (u16*)(smem + 32768);   // [2][256*64]  (65536 B) -> needs smem 98304

  // (a) convert my W_out slice during the encoder window (DEVICE-SCOPE).
  if (bg < 125){
    const int n0c = bg<<8;
    #pragma unroll 1
    for (int i=t; i<256*80; i+=512){
      const int r = i/80, c8 = (i - r*80)<<3;
      u16 o[8];
      #pragma unroll
      for (int jj=0;jj<8;++jj){
        const int c = c8 + jj;
        o[jj] = (c < 636) ? f2bf(W_out[(size_t)(n0c+r)*636 + c]) : (u16)0;
      }
      u32* dst = (u32*)&wout_b[(size_t)(n0c+r)*640 + c8];
      const u32* sv = (const u32*)o;
      #pragma unroll
      for (int jj=0;jj<4;++jj) dev_store_u32(&dst[jj], sv[jj]);
    }
    asm volatile("s_waitcnt vmcnt(0)" ::: "memory");
    __syncthreads();
    if (t==0) dev_store_u32(&ctr[32 + bg], 1u);
  }

  // (b) consume tiles: relaxed polls, staggered sleep
  const int nsleep = 1 + (bg&3);
  #pragma unroll 1
  for (int tau = bg; tau < 3125; tau += 248){
    const int mt = tau/125, nt = tau - mt*125;
    const int m0 = mt<<7, n0 = nt<<8;
    const u32 need = (u32)((2*mt+2 < 49) ? (2*mt+2) : 49);

    if (w==0){
      int cnt = 0;
      while (true){
        u32 v  = (l<4) ? __hip_atomic_load(&ctr[l], __ATOMIC_RELAXED, __HIP_MEMORY_SCOPE_AGENT) : 0xFFFFFFFFu;
        u32 wf = (l==4) ? __hip_atomic_load(&ctr[32 + nt], __ATOMIC_RELAXED, __HIP_MEMORY_SCOPE_AGENT) : 1u;
        if (__all((int)((v >= need) && (wf != 0u)))) break;
        for (int z=0; z<nsleep; ++z) __builtin_amdgcn_s_sleep(16);
        if (++cnt > (1<<22)) break;   // safety
      }
    }
    __syncthreads();

    auto stageA = [&](int k0, int buf){
      #pragma unroll
      for (int i=0;i<2;++i){
        const int rbase = i*64 + w*8;
        const int r = rbase + lr;
        __builtin_amdgcn_global_load_lds(
          (const AS1 void*)(feat + (size_t)(m0+r)*640 + k0 + ((lg^lr)<<3)),
          (AS3 void*)(AL + buf*8192 + rbase*64), 16, 0, 0);
      }
    };
    auto stageB = [&](int k0, int buf){
      #pragma unroll
      for (int i=0;i<4;++i){
        const int rbase = i*64 + w*8;
        const int r = rbase + lr;
        __builtin_amdgcn_global_load_lds(
          (const AS1 void*)(wout_b + (size_t)(n0+r)*640 + k0 + ((lg^lr)<<3)),
          (AS3 void*)(BL + buf*16384 + rbase*64), 16, 0, 0);
      }
    };

    f32x4 acc[4][4] = {};
    stageA(0,0); stageB(0,0);
    asm volatile("s_waitcnt vmcnt(0)" ::: "memory");
    __syncthreads();

    #pragma unroll 1
    for (int ks=0; ks<10; ++ks){
      const int cb = ks&1;
      if (ks < 9){ stageA((ks+1)<<6, cb^1); stageB((ks+1)<<6, cb^1); }
      const u16* Alp = AL + cb*8192;
      const u16* Blp = BL + cb*16384;
      #pragma unroll
      for (int kk=0;kk<2;++kk){
        const int ko = kk*32 + q*8;
        bf16x8 af[4], bfr[4];
        #pragma unroll
        for (int m=0;m<4;++m){
          const int row = wm*64 + m*16 + la;
          af[m] = *(const bf16x8*)&Alp[row*64 + (ko ^ ((row&7)<<3))];
        }
        #pragma unroll
        for (int n=0;n<4;++n){
          const int row = wn*64 + n*16 + la;
          bfr[n] = *(const bf16x8*)&Blp[row*64 + (ko ^ ((row&7)<<3))];
        }
        #pragma unroll
        for (int m=0;m<4;++m)
          #pragma unroll
          for (int n=0;n<4;++n)
            acc[m][n] = __builtin_amdgcn_mfma_f32_16x16x32_bf16(af[m], bfr[n], acc[m][n], 0,0,0);
      }
      asm volatile("s_waitcnt vmcnt(0)" ::: "memory");
      __syncthreads();
    }

    float bv[4];
    #pragma unroll
    for (int n=0;n<4;++n) bv[n] = b_out[n0 + wn*64 + n*16 + la];
    #pragma unroll
    for (int m=0;m<4;++m){
      const int rb = m0 + wm*64 + m*16 + q*4;
      #pragma unroll
      for (int n=0;n<4;++n){
        const int col = n0 + wn*64 + n*16 + la;
        #pragma unroll
        for (int r=0;r<4;++r){
          const int rr = rb + r;
          if (rr < 3136)
            __builtin_nontemporal_store(acc[m][n][r] + bv[n], &Cg[(size_t)rr*32000 + col]);
        }
      }
    }
  }
}

// ---------------- launch ----------------

extern "C" void kernel_launch(void* const* d_in, const int* in_sizes, int n_in,
                              void* d_out, int out_size, void* d_ws, size_t ws_size,
                              hipStream_t stream) {
  const int*   src     = (const int*)d_in[0];
  const int*   trg     = (const int*)d_in[1];
  const float* emb_enc = (const float*)d_in[2];
  const float* W_ih_e  = (const float*)d_in[3];
  const float* W_hh_e  = (const float*)d_in[4];
  const float* b_ih_e  = (const float*)d_in[5];
  const float* b_hh_e  = (const float*)d_in[6];
  const float* emb_dec = (const float*)d_in[7];
  const float* W_ih_d  = (const float*)d_in[8];
  const float* W_hh_d  = (const float*)d_in[9];
  const float* b_ih_d  = (const float*)d_in[10];
  const float* b_hh_d  = (const float*)d_in[11];
  const float* W_out   = (const float*)d_in[12];
  const float* b_out   = (const float*)d_in[13];
  float* out = (float*)d_out;

  char* basep = (char*)d_ws;
  size_t off = 0;
  auto take = [&](size_t b)->char*{ char* p = basep + off; off = (off + b + 255) & ~(size_t)255; return p; };
  u16* feat    = (u16*)take(4096000);   // [3200][640] bf16
  u32* ctr     = (u32*)take(4096);      // flags: [0..3] scan, [32+nt] wout
  u16* wout_b  = (u16*)take(40960000);  // [32000][640]
  u16* wihe_b  = (u16*)take(196608);    // [768][128] permuted
  u16* wihde_b = (u16*)take(196608);    // [768][128] permuted
  u16* wihdc_b = (u16*)take(393216);    // [768][256] permuted
  u16* whhe_b  = (u16*)take(393216);    // [768][256] permuted
  u16* whhd_b  = (u16*)take(393216);    // [768][256] permuted
  u16* encx_b  = (u16*)take(819200);    // [3200][128]
  u16* dece_b  = (u16*)take(819200);    // [3200][128]
  u16* enc_gi  = (u16*)take(4915200);   // [3200][768] bf16 (permuted cols)
  u16* dec_gi  = (u16*)take(4915200);   // [3200][768] bf16 (permuted cols)
  float* bihe_p = (float*)take(3072);
  float* bihd_p = (float*)take(3072);
  float* bhhe_p = (float*)take(3072);
  float* bhhd_p = (float*)take(3072);
  (void)in_sizes; (void)n_in; (void)out_size; (void)ws_size;

  // zero flags and output row 0
  zero_bytes<<<1, 256, 0, stream>>>((uint4*)ctr, (size_t)(4096/16));
  zero_bytes<<<2000, 256, 0, stream>>>((uint4*)out, (size_t)(8192000/16));

  // permuted gate-weight packs
  pad_convert_g<<<384, 256, 0, stream>>>(W_ih_e, 128,   0, 128, wihe_b, 128);
  pad_convert_g<<<384, 256, 0, stream>>>(W_ih_d, 382,   0, 128, wihde_b, 128);
  pad_convert_g<<<768, 256, 0, stream>>>(W_ih_d, 382, 128, 254, wihdc_b, 256);
  pad_convert_g<<<768, 256, 0, stream>>>(W_hh_e, 254,   0, 254, whhe_b, 256);
  pad_convert_g<<<768, 256, 0, stream>>>(W_hh_d, 254,   0, 254, whhd_b, 256);

  pad_bias_comb<<<3, 256, 0, stream>>>(b_ih_e, b_hh_e, bihe_p);
  pad_bias_comb<<<3, 256, 0, stream>>>(b_ih_d, b_hh_d, bihd_p);
  pad_bias_g<<<3, 256, 0, stream>>>(b_hh_e, bhhe_p);
  pad_bias_g<<<3, 256, 0, stream>>>(b_hh_d, bhhd_p);

  gather_enc<<<1600, 256, 0, stream>>>(src, emb_enc, encx_b);
  gather_dec<<<1600, 256, 0, stream>>>(trg, emb_dec, dece_b, feat);

  // gi = bf16( x @ W_ih^T + (b_ih + b_hh_rz) )  (M=3200, N=768 permuted, K=128)
  gemm_bt16<<<25*6, 256, 0, stream>>>(encx_b, 128, wihe_b, 128, enc_gi, (long long)768, bihe_p, 128, 25, 3200);
  gemm_bt16<<<25*6, 256, 0, stream>>>(dece_b, 128, wihde_b, 128, dec_gi, (long long)768, bihd_p, 128, 25, 3200);

  // fused: scan (blocks 0-3) + W_out convert + output GEMM (blocks 4-251)
  fused_scan_gemm<<<252, 512, 0, stream>>>(whhe_b, whhd_b, wihdc_b, bhhe_p, bhhd_p,
                                           enc_gi, dec_gi, feat, wout_b, W_out,
                                           out + (size_t)64*32000, b_out, ctr);
}

// Round 16
// 600.732 us; speedup vs baseline: 1.2952x; 1.2952x over previous
//
#include <hip/hip_runtime.h>
#include <cstdint>
#include <cstddef>

typedef unsigned short u16;
typedef unsigned int u32;
typedef unsigned long long u64;
typedef __attribute__((ext_vector_type(8))) short bf16x8;
typedef __attribute__((ext_vector_type(4))) float f32x4;

#define AS1 __attribute__((address_space(1)))
#define AS3 __attribute__((address_space(3)))

__device__ __forceinline__ float bf2f(u16 u){ u32 x = ((u32)u)<<16; float f; __builtin_memcpy(&f,&x,4); return f; }
__device__ __forceinline__ u16 f2bf(float f){ u32 x; __builtin_memcpy(&x,&f,4); u32 r=(x+0x7FFFu+((x>>16)&1u))>>16; return (u16)r; }

__device__ __forceinline__ float fast_sig(float x){
  return __fdividef(1.f, 1.f + __expf(-x));
}
__device__ __forceinline__ float fast_tanh(float x){
  float e = __expf(2.f*x);
  return 1.f - __fdividef(2.f, e + 1.f);
}

// device-scope stores (write-through past the producer XCD's private L2).
// REQUIRED for data produced here and consumed by blocks on other XCDs
// (feat, wout_b, flags). Plain stores strand dirty lines (R10/R11 bug).
__device__ __forceinline__ void dev_store_u16(u16* p, u16 v){
  __hip_atomic_store(p, v, __ATOMIC_RELAXED, __HIP_MEMORY_SCOPE_AGENT);
}
__device__ __forceinline__ void dev_store_u32(u32* p, u32 v){
  __hip_atomic_store(p, v, __ATOMIC_RELAXED, __HIP_MEMORY_SCOPE_AGENT);
}
__device__ __forceinline__ void dev_store_u64(u64* p, u64 v){
  __hip_atomic_store(p, v, __ATOMIC_RELAXED, __HIP_MEMORY_SCOPE_AGENT);
}

// ---------------- utility kernels ----------------

__global__ void zero_bytes(uint4* p, size_t n16){
  size_t i = (size_t)blockIdx.x*blockDim.x + threadIdx.x;
  size_t st = (size_t)gridDim.x*blockDim.x;
  uint4 z; z.x=0u; z.y=0u; z.z=0u; z.w=0u;
  for (; i<n16; i+=st) p[i]=z;
}

// gate-matrix pad+convert with wave-local (r,z,n) row permutation
__global__ void pad_convert_g(const float* __restrict__ src, int src_ld, int c0, int vcols,
                              u16* __restrict__ dst, int dcols){
  int i = blockIdx.x*256 + threadIdx.x;
  int tot = 768*dcols;
  if (i >= tot) return;
  int p = i/dcols, c = i - p*dcols;
  int wv = p/96, rem = p - wv*96, sec = rem>>5, u = rem&31;
  int j = wv*32 + u;
  float v = 0.f;
  if (j < 254 && c < vcols) v = src[(size_t)(sec*254 + j)*src_ld + c0 + c];
  dst[i] = f2bf(v);
}

// combined gi bias: b_ih + b_hh for r,z sections (permuted)
__global__ void pad_bias_comb(const float* __restrict__ ih, const float* __restrict__ hh,
                              float* __restrict__ dst){
  int p = blockIdx.x*256 + threadIdx.x;
  if (p >= 768) return;
  int wv = p/96, rem = p - wv*96, sec = rem>>5, u = rem&31;
  int j = wv*32 + u;
  float v = 0.f;
  if (j < 254){ v = ih[sec*254 + j]; if (sec < 2) v += hh[sec*254 + j]; }
  dst[p] = v;
}

__global__ void pad_bias_g(const float* __restrict__ src, float* __restrict__ dst){
  int p = blockIdx.x*256 + threadIdx.x;
  if (p >= 768) return;
  int wv = p/96, rem = p - wv*96, sec = rem>>5, u = rem&31;
  int j = wv*32 + u;
  dst[p] = (j<254) ? src[sec*254 + j] : 0.f;
}

__global__ void gather_enc(const int* __restrict__ idx, const float* __restrict__ emb, u16* __restrict__ dst){
  int i = blockIdx.x*256 + threadIdx.x;
  int r = i>>7, k = i&127;
  dst[i] = f2bf(emb[(size_t)idx[r]*128 + k]);
}

__global__ void gather_dec(const int* __restrict__ idx, const float* __restrict__ emb,
                           u16* __restrict__ dst, u16* __restrict__ feat){
  int i = blockIdx.x*256 + threadIdx.x;
  int r = i>>7, k = i&127;
  u16 v = 0;
  if (r < 3136) v = f2bf(emb[(size_t)idx[r]*128 + k]);
  dst[i] = v;
  if (r < 3136) feat[(size_t)r*640 + 508 + k] = v;   // cross-kernel: HSA release WB
}

// ------- gi GEMM (4-wave 128x128, R4 structure), bf16 OUTPUT, col bias -------

__global__ __launch_bounds__(256) void gemm_bt16(
  const u16* __restrict__ A, int lda,
  const u16* __restrict__ B, int ldb,
  u16* __restrict__ C, long long ldc,
  const float* __restrict__ bias,
  int K, int Mtiles, int Mstore)
{
  __shared__ __align__(16) u16 Abuf[2][128*64];
  __shared__ __align__(16) u16 Bbuf[2][128*64];
  const int t = threadIdx.x;
  const int w = t>>6, l = t&63;
  const int wm = w>>1, wn = w&1;
  const int mt = blockIdx.x % Mtiles, nt = blockIdx.x / Mtiles;
  const int m0 = mt<<7, n0 = nt<<7;

  const int lr = l>>3, lg = l&7;

  auto stage = [&](const u16* __restrict__ G, int ld, int base0, int k0, u16* Lbuf){
    #pragma unroll
    for (int i=0;i<4;++i){
      const int rbase = i*32 + w*8;
      const int r = rbase + lr;
      const int gsw = lg ^ (r&7);
      __builtin_amdgcn_global_load_lds(
        (const AS1 void*)(G + (size_t)(base0+r)*ld + k0 + gsw*8),
        (AS3 void*)(Lbuf + rbase*64), 16, 0, 0);
    }
  };

  f32x4 acc[4][4] = {};
  const int ksteps = K>>6;

  stage(A, lda, m0, 0, Abuf[0]);
  stage(B, ldb, n0, 0, Bbuf[0]);
  asm volatile("s_waitcnt vmcnt(0)" ::: "memory");
  __syncthreads();

  for (int ks=0; ks<ksteps; ++ks){
    const int cb = ks&1;
    if (ks+1 < ksteps){
      stage(A, lda, m0, (ks+1)<<6, Abuf[cb^1]);
      stage(B, ldb, n0, (ks+1)<<6, Bbuf[cb^1]);
    }
    const u16* Al = Abuf[cb];
    const u16* Bl = Bbuf[cb];
    #pragma unroll
    for (int kk=0;kk<2;++kk){
      const int ko = kk*32 + (l>>4)*8;
      bf16x8 af[4], bfr[4];
      #pragma unroll
      for (int m=0;m<4;++m){
        const int row = wm*64+m*16+(l&15);
        af[m] = *(const bf16x8*)&Al[row*64 + (ko ^ ((row&7)<<3))];
      }
      #pragma unroll
      for (int n=0;n<4;++n){
        const int row = wn*64+n*16+(l&15);
        bfr[n] = *(const bf16x8*)&Bl[row*64 + (ko ^ ((row&7)<<3))];
      }
      #pragma unroll
      for (int m=0;m<4;++m)
        #pragma unroll
        for (int n=0;n<4;++n)
          acc[m][n] = __builtin_amdgcn_mfma_f32_16x16x32_bf16(af[m], bfr[n], acc[m][n], 0,0,0);
    }
    asm volatile("s_waitcnt vmcnt(0)" ::: "memory");
    __syncthreads();
  }

  float bv[4];
  #pragma unroll
  for (int n=0;n<4;++n) bv[n] = bias[n0 + wn*64 + n*16 + (l&15)];
  #pragma unroll
  for (int m=0;m<4;++m){
    const int rb = m0 + wm*64 + m*16 + (l>>4)*4;
    #pragma unroll
    for (int n=0;n<4;++n){
      const int col = n0 + wn*64 + n*16 + (l&15);
      #pragma unroll
      for (int r=0;r<4;++r){
        const int rr = rb + r;
        if (rr < Mstore) C[(size_t)rr*ldc + col] = f2bf(acc[m][n][r] + bv[n]);
      }
    }
  }
}

// ---------------- FUSED scan + output-GEMM (producer-consumer) ----------------
// Blocks 0-3: GRU scan — R12's proven LINEAR gi staging/gate reads (no swizzle:
//   R15 showed pre-swizzled global sources break global_load_lds coalescing),
//   plus the three addressing-neutral wins validated in R15:
//   (1) h carried in registers, (2) ctx patched into dec_gi once,
//   (3) vectorized feat h-row stores at step top (vmcnt(3) ledger).
// Blocks 4-251: W_out convert (device-scope) + gated tile consume.
// smem = max(scan 90624, gemm 98304) = 98304 (R14 lesson).

__global__ __launch_bounds__(512,1) void fused_scan_gemm(
  const u16* Whhe, const u16* Whhd, const u16* Wihdc,
  const float* bhhe, const float* bhhd,
  const u16* enc_gi, u16* dec_gi,
  u16* feat, u16* wout_b, const float* W_out,
  float* Cg, const float* b_out, u32* ctr)
{
  __shared__ __align__(16) char smem[98304];
  const int t = threadIdx.x;
  const int w = t>>6, l = t&63;

  if (blockIdx.x < 4){
    // ================= scan branch =================
    const int g = blockIdx.x;
    const int la = l&15, q = l>>4;
    const int brow0 = g*16;

    u16* hb  = (u16*)smem;               // [2][16][264]  (16896 B)
    u16* gib = (u16*)(smem + 16896);     // [3][16][768]  (73728 B), LINEAR

    bf16x8 Bf[48];

    auto loadW = [&](const u16* __restrict__ W){
      #pragma unroll
      for (int nt=0; nt<6; ++nt)
        #pragma unroll
        for (int kk=0; kk<8; ++kk)
          Bf[nt*8+kk] = *(const bf16x8*)&W[(size_t)(w*96 + nt*16 + la)*256 + kk*32 + q*8];
    };

    // bf16 gi stage: 24KB per step, 3 global_load_lds per thread, LINEAR
    // (coalesced per-lane global addresses -- the R12 form).
    auto stage = [&](const u16* __restrict__ gsrc, int step, u16* dstL){
      const u16* src = gsrc + (size_t)(step*64 + brow0)*768;
      #pragma unroll
      for (int i=0;i<3;++i){
        const int off = i*4096 + w*512;     // u16 units, wave-uniform
        __builtin_amdgcn_global_load_lds((const AS1 void*)(src + off + l*8),
                                         (AS3 void*)(dstL + off), 16, 0, 0);
      }
    };

    auto mm = [&](const u16* hsrc, f32x4* acc){
      #pragma unroll
      for (int kk=0; kk<8; ++kk){
        bf16x8 a = *(const bf16x8*)&hsrc[la*264 + kk*32 + q*8];
        #pragma unroll
        for (int nt=0; nt<6; ++nt)
          acc[nt] = __builtin_amdgcn_mfma_f32_16x16x32_bf16(a, Bf[nt*8+kk], acc[nt], 0,0,0);
      }
    };

    for (int i=t; i<2*16*264; i+=512) hb[i] = 0;
    loadW(Whhe);
    float bn[2];
    #pragma unroll
    for (int tl=0; tl<2; ++tl) bn[tl] = bhhe[w*96 + tl*16 + la + 64];
    float hreg[8] = {};
    stage(enc_gi, 0, gib);
    stage(enc_gi, 1, gib + 12288);
    asm volatile("s_waitcnt vmcnt(0) lgkmcnt(0)" ::: "memory");
    __builtin_amdgcn_s_barrier();

    // ---- encoder: 50 steps ----
    #pragma unroll 1
    for (int s=0; s<50; ++s){
      const int hc = s&1;
      const u16* gT = gib + (s%3)*12288;
      if (s+2 < 50) stage(enc_gi, s+2, gib + ((s+2)%3)*12288);
      f32x4 acc[6] = {};
      mm(hb + hc*4224, acc);
      #pragma unroll
      for (int tl=0; tl<2; ++tl){
        const int pb = w*96 + tl*16 + la;
        const int j  = w*32 + tl*16 + la;
        #pragma unroll
        for (int r=0;r<4;++r){
          const int b = q*4 + r;
          const float rg = fast_sig(bf2f(gT[b*768 + pb])      + acc[tl][r]);
          const float zg = fast_sig(bf2f(gT[b*768 + pb + 32]) + acc[2+tl][r]);
          const float ng = fast_tanh(bf2f(gT[b*768 + pb + 64]) + rg*(acc[4+tl][r] + bn[tl]));
          const float h2 = (1.f-zg)*ng + zg*hreg[tl*4+r];
          hreg[tl*4+r] = h2;
          hb[(hc^1)*4224 + b*264 + j] = f2bf(h2);
        }
      }
      if (s+2 < 50) asm volatile("s_waitcnt vmcnt(3) lgkmcnt(0)" ::: "memory");
      else          asm volatile("s_waitcnt vmcnt(0) lgkmcnt(0)" ::: "memory");
      __builtin_amdgcn_s_barrier();
    }
    // context = h(50) in hb[0] and hreg

    // ---- ctx gate input (step-invariant) -> ctxb (aliases gib[2], dead after patch) ----
    loadW(Wihdc);
    u16* ctxb = gib + 2*12288;           // [16][768]
    {
      f32x4 acc[6] = {};
      mm(hb, acc);
      #pragma unroll
      for (int nt=0; nt<6; ++nt)
        #pragma unroll
        for (int r=0;r<4;++r)
          ctxb[(q*4+r)*768 + w*96 + nt*16 + la] = f2bf(acc[nt][r]);
    }
    asm volatile("s_waitcnt lgkmcnt(0)" ::: "memory");
    __builtin_amdgcn_s_barrier();

    // ---- patch ctx into dec_gi ONCE (coalesced 16B RMW; self-XCD consumer) ----
    #pragma unroll 1
    for (int idx=t; idx<49*16*96; idx+=512){
      const int row = idx/96, cch = idx - row*96;
      const int tt2 = row>>4, b = row&15;
      u16* gp = dec_gi + (size_t)(tt2*64 + brow0 + b)*768 + cch*8;
      uint4 a = *(uint4*)gp;
      const uint4 c = *(const uint4*)&ctxb[b*768 + cch*8];
      auto addbf = [](u32 x, u32 y)->u32{
        u32 lo = (u32)f2bf(bf2f((u16)(x&0xffff)) + bf2f((u16)(y&0xffff)));
        u32 hi = (u32)f2bf(bf2f((u16)(x>>16))    + bf2f((u16)(y>>16)));
        return lo | (hi<<16);
      };
      a.x=addbf(a.x,c.x); a.y=addbf(a.y,c.y); a.z=addbf(a.z,c.z); a.w=addbf(a.w,c.w);
      *(uint4*)gp = a;
    }
    asm volatile("s_waitcnt vmcnt(0)" ::: "memory");
    __builtin_amdgcn_s_barrier();

    // ---- stage decoder steps 0,1 (patched dec_gi); feat ctx cols ----
    stage(dec_gi, 0, gib);
    stage(dec_gi, 1, gib + 12288);

    #pragma unroll 1
    for (int i=t; i<49*2048; i+=512){
      const int tt = i>>11, rem = i&2047, b = rem>>7, c2 = rem&127;
      if (c2 < 127){
        u32 v = *(const u32*)&hb[b*264 + c2*2];
        dev_store_u32((u32*)&feat[(size_t)(tt*64 + brow0 + b)*640 + 254 + c2*2], v);
      }
    }

    loadW(Whhd);
    #pragma unroll
    for (int tl=0; tl<2; ++tl) bn[tl] = bhhd[w*96 + tl*16 + la + 64];
    asm volatile("s_waitcnt vmcnt(0) lgkmcnt(0)" ::: "memory");
    __builtin_amdgcn_s_barrier();

    // ---- decoder: 49 steps; feat(tt-1) written vectorized at step top ----
    #pragma unroll 1
    for (int tt=0; tt<49; ++tt){
      const int hc = tt&1;
      const u16* gT = gib + (tt%3)*12288;
      if (tt >= 1){
        #pragma unroll
        for (int i0=t; i0<1024; i0+=512){
          const int b = i0>>6, c = i0&63;
          const u16* hrow = hb + hc*4224 + b*264;
          u16* frow = feat + (size_t)((tt-1)*64 + brow0 + b)*640;
          if (c < 63) dev_store_u64((u64*)(frow + c*4), *(const u64*)(hrow + c*4));
          else        dev_store_u32((u32*)(frow + 252), *(const u32*)(hrow + 252));
        }
      }
      if (tt+2 < 49) stage(dec_gi, tt+2, gib + ((tt+2)%3)*12288);
      f32x4 acc[6] = {};
      mm(hb + hc*4224, acc);
      #pragma unroll
      for (int tl=0; tl<2; ++tl){
        const int pb = w*96 + tl*16 + la;
        const int j  = w*32 + tl*16 + la;
        #pragma unroll
        for (int r=0;r<4;++r){
          const int b = q*4 + r;
          const float rg = fast_sig(bf2f(gT[b*768 + pb])      + acc[tl][r]);
          const float zg = fast_sig(bf2f(gT[b*768 + pb + 32]) + acc[2+tl][r]);
          const float ng = fast_tanh(bf2f(gT[b*768 + pb + 64]) + rg*(acc[4+tl][r] + bn[tl]));
          const float h2 = (1.f-zg)*ng + zg*hreg[tl*4+r];
          hreg[tl*4+r] = h2;
          hb[(hc^1)*4224 + b*264 + j] = f2bf(h2);
        }
      }
      // ledger: in-flight at wait = stage(tt+2):3 + feat(tt-1):2 + stage(tt+1):3
      // from prior iter -> vmcnt(3) drains feat(tt-1)+stage(tt+1), keeps stage(tt+2).
      if (tt+2 < 49) asm volatile("s_waitcnt vmcnt(3) lgkmcnt(0)" ::: "memory");
      else           asm volatile("s_waitcnt vmcnt(0) lgkmcnt(0)" ::: "memory");
      __builtin_amdgcn_s_barrier();
      if (t==0) dev_store_u32(&ctr[g], (u32)tt);   // steps 0..tt-1 visible
    }
    // final: feat rows for step 48 from hb[1] (h(49))
    #pragma unroll
    for (int i0=t; i0<1024; i0+=512){
      const int b = i0>>6, c = i0&63;
      const u16* hrow = hb + 4224 + b*264;
      u16* frow = feat + (size_t)(48*64 + brow0 + b)*640;
      if (c < 63) dev_store_u64((u64*)(frow + c*4), *(const u64*)(hrow + c*4));
      else        dev_store_u32((u32*)(frow + 252), *(const u32*)(hrow + 252));
    }
    asm volatile("s_waitcnt vmcnt(0)" ::: "memory");
    __syncthreads();
    if (t==0) dev_store_u32(&ctr[g], 49u);         // all steps visible
    return;
  }

  // ================= gemm branch =================
  const int bg = blockIdx.x - 4;
  const int wm = w>>2, wn = w&3;
  const int la = l&15, q = l>>4;
  const int lr = l>>3, lg = l&7;

  u16* AL = (u16*)smem;             // [2][128*64]  (32768 B)
  u16* BL = (u16*)(smem + 32768);   // [2][256*64]  (65536 B) -> smem 98304

  // (a) convert my W_out slice during the encoder window (DEVICE-SCOPE).
  if (bg < 125){
    const int n0c = bg<<8;
    #pragma unroll 1
    for (int i=t; i<256*80; i+=512){
      const int r = i/80, c8 = (i - r*80)<<3;
      u16 o[8];
      #pragma unroll
      for (int jj=0;jj<8;++jj){
        const int c = c8 + jj;
        o[jj] = (c < 636) ? f2bf(W_out[(size_t)(n0c+r)*636 + c]) : (u16)0;
      }
      u32* dst = (u32*)&wout_b[(size_t)(n0c+r)*640 + c8];
      const u32* sv = (const u32*)o;
      #pragma unroll
      for (int jj=0;jj<4;++jj) dev_store_u32(&dst[jj], sv[jj]);
    }
    asm volatile("s_waitcnt vmcnt(0)" ::: "memory");
    __syncthreads();
    if (t==0) dev_store_u32(&ctr[32 + bg], 1u);
  }

  // (b) consume tiles: relaxed polls, staggered sleep
  const int nsleep = 1 + (bg&3);
  #pragma unroll 1
  for (int tau = bg; tau < 3125; tau += 248){
    const int mt = tau/125, nt = tau - mt*125;
    const int m0 = mt<<7, n0 = nt<<8;
    const u32 need = (u32)((2*mt+2 < 49) ? (2*mt+2) : 49);

    if (w==0){
      int cnt = 0;
      while (true){
        u32 v  = (l<4) ? __hip_atomic_load(&ctr[l], __ATOMIC_RELAXED, __HIP_MEMORY_SCOPE_AGENT) : 0xFFFFFFFFu;
        u32 wf = (l==4) ? __hip_atomic_load(&ctr[32 + nt], __ATOMIC_RELAXED, __HIP_MEMORY_SCOPE_AGENT) : 1u;
        if (__all((int)((v >= need) && (wf != 0u)))) break;
        for (int z=0; z<nsleep; ++z) __builtin_amdgcn_s_sleep(16);
        if (++cnt > (1<<22)) break;   // safety
      }
    }
    __syncthreads();

    auto stageA = [&](int k0, int buf){
      #pragma unroll
      for (int i=0;i<2;++i){
        const int rbase = i*64 + w*8;
        const int r = rbase + lr;
        __builtin_amdgcn_global_load_lds(
          (const AS1 void*)(feat + (size_t)(m0+r)*640 + k0 + ((lg^lr)<<3)),
          (AS3 void*)(AL + buf*8192 + rbase*64), 16, 0, 0);
      }
    };
    auto stageB = [&](int k0, int buf){
      #pragma unroll
      for (int i=0;i<4;++i){
        const int rbase = i*64 + w*8;
        const int r = rbase + lr;
        __builtin_amdgcn_global_load_lds(
          (const AS1 void*)(wout_b + (size_t)(n0+r)*640 + k0 + ((lg^lr)<<3)),
          (AS3 void*)(BL + buf*16384 + rbase*64), 16, 0, 0);
      }
    };

    f32x4 acc[4][4] = {};
    stageA(0,0); stageB(0,0);
    asm volatile("s_waitcnt vmcnt(0)" ::: "memory");
    __syncthreads();

    #pragma unroll 1
    for (int ks=0; ks<10; ++ks){
      const int cb = ks&1;
      if (ks < 9){ stageA((ks+1)<<6, cb^1); stageB((ks+1)<<6, cb^1); }
      const u16* Alp = AL + cb*8192;
      const u16* Blp = BL + cb*16384;
      #pragma unroll
      for (int kk=0;kk<2;++kk){
        const int ko = kk*32 + q*8;
        bf16x8 af[4], bfr[4];
        #pragma unroll
        for (int m=0;m<4;++m){
          const int row = wm*64 + m*16 + la;
          af[m] = *(const bf16x8*)&Alp[row*64 + (ko ^ ((row&7)<<3))];
        }
        #pragma unroll
        for (int n=0;n<4;++n){
          const int row = wn*64 + n*16 + la;
          bfr[n] = *(const bf16x8*)&Blp[row*64 + (ko ^ ((row&7)<<3))];
        }
        #pragma unroll
        for (int m=0;m<4;++m)
          #pragma unroll
          for (int n=0;n<4;++n)
            acc[m][n] = __builtin_amdgcn_mfma_f32_16x16x32_bf16(af[m], bfr[n], acc[m][n], 0,0,0);
      }
      asm volatile("s_waitcnt vmcnt(0)" ::: "memory");
      __syncthreads();
    }

    float bv[4];
    #pragma unroll
    for (int n=0;n<4;++n) bv[n] = b_out[n0 + wn*64 + n*16 + la];
    #pragma unroll
    for (int m=0;m<4;++m){
      const int rb = m0 + wm*64 + m*16 + q*4;
      #pragma unroll
      for (int n=0;n<4;++n){
        const int col = n0 + wn*64 + n*16 + la;
        #pragma unroll
        for (int r=0;r<4;++r){
          const int rr = rb + r;
          if (rr < 3136)
            __builtin_nontemporal_store(acc[m][n][r] + bv[n], &Cg[(size_t)rr*32000 + col]);
        }
      }
    }
  }
}

// ---------------- launch ----------------

extern "C" void kernel_launch(void* const* d_in, const int* in_sizes, int n_in,
                              void* d_out, int out_size, void* d_ws, size_t ws_size,
                              hipStream_t stream) {
  const int*   src     = (const int*)d_in[0];
  const int*   trg     = (const int*)d_in[1];
  const float* emb_enc = (const float*)d_in[2];
  const float* W_ih_e  = (const float*)d_in[3];
  const float* W_hh_e  = (const float*)d_in[4];
  const float* b_ih_e  = (const float*)d_in[5];
  const float* b_hh_e  = (const float*)d_in[6];
  const float* emb_dec = (const float*)d_in[7];
  const float* W_ih_d  = (const float*)d_in[8];
  const float* W_hh_d  = (const float*)d_in[9];
  const float* b_ih_d  = (const float*)d_in[10];
  const float* b_hh_d  = (const float*)d_in[11];
  const float* W_out   = (const float*)d_in[12];
  const float* b_out   = (const float*)d_in[13];
  float* out = (float*)d_out;

  char* basep = (char*)d_ws;
  size_t off = 0;
  auto take = [&](size_t b)->char*{ char* p = basep + off; off = (off + b + 255) & ~(size_t)255; return p; };
  u16* feat    = (u16*)take(4096000);   // [3200][640] bf16
  u32* ctr     = (u32*)take(4096);      // flags: [0..3] scan, [32+nt] wout
  u16* wout_b  = (u16*)take(40960000);  // [32000][640]
  u16* wihe_b  = (u16*)take(196608);    // [768][128] permuted
  u16* wihde_b = (u16*)take(196608);    // [768][128] permuted
  u16* wihdc_b = (u16*)take(393216);    // [768][256] permuted
  u16* whhe_b  = (u16*)take(393216);    // [768][256] permuted
  u16* whhd_b  = (u16*)take(393216);    // [768][256] permuted
  u16* encx_b  = (u16*)take(819200);    // [3200][128]
  u16* dece_b  = (u16*)take(819200);    // [3200][128]
  u16* enc_gi  = (u16*)take(4915200);   // [3200][768] bf16 (permuted cols)
  u16* dec_gi  = (u16*)take(4915200);   // [3200][768] bf16 (permuted cols)
  float* bihe_p = (float*)take(3072);
  float* bihd_p = (float*)take(3072);
  float* bhhe_p = (float*)take(3072);
  float* bhhd_p = (float*)take(3072);
  (void)in_sizes; (void)n_in; (void)out_size; (void)ws_size;

  // zero flags and output row 0
  zero_bytes<<<1, 256, 0, stream>>>((uint4*)ctr, (size_t)(4096/16));
  zero_bytes<<<2000, 256, 0, stream>>>((uint4*)out, (size_t)(8192000/16));

  // permuted gate-weight packs
  pad_convert_g<<<384, 256, 0, stream>>>(W_ih_e, 128,   0, 128, wihe_b, 128);
  pad_convert_g<<<384, 256, 0, stream>>>(W_ih_d, 382,   0, 128, wihde_b, 128);
  pad_convert_g<<<768, 256, 0, stream>>>(W_ih_d, 382, 128, 254, wihdc_b, 256);
  pad_convert_g<<<768, 256, 0, stream>>>(W_hh_e, 254,   0, 254, whhe_b, 256);
  pad_convert_g<<<768, 256, 0, stream>>>(W_hh_d, 254,   0, 254, whhd_b, 256);

  pad_bias_comb<<<3, 256, 0, stream>>>(b_ih_e, b_hh_e, bihe_p);
  pad_bias_comb<<<3, 256, 0, stream>>>(b_ih_d, b_hh_d, bihd_p);
  pad_bias_g<<<3, 256, 0, stream>>>(b_hh_e, bhhe_p);
  pad_bias_g<<<3, 256, 0, stream>>>(b_hh_d, bhhd_p);

  gather_enc<<<1600, 256, 0, stream>>>(src, emb_enc, encx_b);
  gather_dec<<<1600, 256, 0, stream>>>(trg, emb_dec, dece_b, feat);

  // gi = bf16( x @ W_ih^T + (b_ih + b_hh_rz) )  (M=3200, N=768 permuted, K=128)
  gemm_bt16<<<25*6, 256, 0, stream>>>(encx_b, 128, wihe_b, 128, enc_gi, (long long)768, bihe_p, 128, 25, 3200);
  gemm_bt16<<<25*6, 256, 0, stream>>>(dece_b, 128, wihde_b, 128, dec_gi, (long long)768, bihd_p, 128, 25, 3200);

  // fused: scan (blocks 0-3) + W_out convert + output GEMM (blocks 4-251)
  fused_scan_gemm<<<252, 512, 0, stream>>>(whhe_b, whhd_b, wihdc_b, bhhe_p, bhhd_p,
                                           enc_gi, dec_gi, feat, wout_b, W_out,
                                           out + (size_t)64*32000, b_out, ctr);
}

// Round 17
// 514.803 us; speedup vs baseline: 1.5114x; 1.1669x over previous
//
#include <hip/hip_runtime.h>
#include <cstdint>
#include <cstddef>

typedef unsigned short u16;
typedef unsigned int u32;
typedef unsigned long long u64;
typedef __attribute__((ext_vector_type(8))) short bf16x8;
typedef __attribute__((ext_vector_type(4))) float f32x4;

#define AS1 __attribute__((address_space(1)))
#define AS3 __attribute__((address_space(3)))

__device__ __forceinline__ float bf2f(u16 u){ u32 x = ((u32)u)<<16; float f; __builtin_memcpy(&f,&x,4); return f; }
__device__ __forceinline__ u16 f2bf(float f){ u32 x; __builtin_memcpy(&x,&f,4); u32 r=(x+0x7FFFu+((x>>16)&1u))>>16; return (u16)r; }

__device__ __forceinline__ float fast_sig(float x){
  return __fdividef(1.f, 1.f + __expf(-x));
}
__device__ __forceinline__ float fast_tanh(float x){
  float e = __expf(2.f*x);
  return 1.f - __fdividef(2.f, e + 1.f);
}

// device-scope stores (write-through past the producer XCD's private L2).
// REQUIRED for data produced here and consumed by blocks on other XCDs
// (feat, wout_b, flags). Plain stores strand dirty lines (R10/R11 bug).
__device__ __forceinline__ void dev_store_u16(u16* p, u16 v){
  __hip_atomic_store(p, v, __ATOMIC_RELAXED, __HIP_MEMORY_SCOPE_AGENT);
}
__device__ __forceinline__ void dev_store_u32(u32* p, u32 v){
  __hip_atomic_store(p, v, __ATOMIC_RELAXED, __HIP_MEMORY_SCOPE_AGENT);
}

// ---------------- utility kernels ----------------

__global__ void zero_bytes(uint4* p, size_t n16){
  size_t i = (size_t)blockIdx.x*blockDim.x + threadIdx.x;
  size_t st = (size_t)gridDim.x*blockDim.x;
  uint4 z; z.x=0u; z.y=0u; z.z=0u; z.w=0u;
  for (; i<n16; i+=st) p[i]=z;
}

// gate-matrix pad+convert with wave-local (r,z,n) row permutation
__global__ void pad_convert_g(const float* __restrict__ src, int src_ld, int c0, int vcols,
                              u16* __restrict__ dst, int dcols){
  int i = blockIdx.x*256 + threadIdx.x;
  int tot = 768*dcols;
  if (i >= tot) return;
  int p = i/dcols, c = i - p*dcols;
  int wv = p/96, rem = p - wv*96, sec = rem>>5, u = rem&31;
  int j = wv*32 + u;
  float v = 0.f;
  if (j < 254 && c < vcols) v = src[(size_t)(sec*254 + j)*src_ld + c0 + c];
  dst[i] = f2bf(v);
}

// combined gi bias: b_ih + b_hh for r,z sections (permuted)
__global__ void pad_bias_comb(const float* __restrict__ ih, const float* __restrict__ hh,
                              float* __restrict__ dst){
  int p = blockIdx.x*256 + threadIdx.x;
  if (p >= 768) return;
  int wv = p/96, rem = p - wv*96, sec = rem>>5, u = rem&31;
  int j = wv*32 + u;
  float v = 0.f;
  if (j < 254){ v = ih[sec*254 + j]; if (sec < 2) v += hh[sec*254 + j]; }
  dst[p] = v;
}

__global__ void pad_bias_g(const float* __restrict__ src, float* __restrict__ dst){
  int p = blockIdx.x*256 + threadIdx.x;
  if (p >= 768) return;
  int wv = p/96, rem = p - wv*96, sec = rem>>5, u = rem&31;
  int j = wv*32 + u;
  dst[p] = (j<254) ? src[sec*254 + j] : 0.f;
}

__global__ void gather_enc(const int* __restrict__ idx, const float* __restrict__ emb, u16* __restrict__ dst){
  int i = blockIdx.x*256 + threadIdx.x;
  int r = i>>7, k = i&127;
  dst[i] = f2bf(emb[(size_t)idx[r]*128 + k]);
}

__global__ void gather_dec(const int* __restrict__ idx, const float* __restrict__ emb,
                           u16* __restrict__ dst, u16* __restrict__ feat){
  int i = blockIdx.x*256 + threadIdx.x;
  int r = i>>7, k = i&127;
  u16 v = 0;
  if (r < 3136) v = f2bf(emb[(size_t)idx[r]*128 + k]);
  dst[i] = v;
  if (r < 3136) feat[(size_t)r*640 + 508 + k] = v;   // cross-kernel: HSA release WB
}

// ------- gi GEMM (4-wave 128x128, R4 structure), bf16 OUTPUT, col bias -------

__global__ __launch_bounds__(256) void gemm_bt16(
  const u16* __restrict__ A, int lda,
  const u16* __restrict__ B, int ldb,
  u16* __restrict__ C, long long ldc,
  const float* __restrict__ bias,
  int K, int Mtiles, int Mstore)
{
  __shared__ __align__(16) u16 Abuf[2][128*64];
  __shared__ __align__(16) u16 Bbuf[2][128*64];
  const int t = threadIdx.x;
  const int w = t>>6, l = t&63;
  const int wm = w>>1, wn = w&1;
  const int mt = blockIdx.x % Mtiles, nt = blockIdx.x / Mtiles;
  const int m0 = mt<<7, n0 = nt<<7;

  const int lr = l>>3, lg = l&7;

  auto stage = [&](const u16* __restrict__ G, int ld, int base0, int k0, u16* Lbuf){
    #pragma unroll
    for (int i=0;i<4;++i){
      const int rbase = i*32 + w*8;
      const int r = rbase + lr;
      const int gsw = lg ^ (r&7);
      __builtin_amdgcn_global_load_lds(
        (const AS1 void*)(G + (size_t)(base0+r)*ld + k0 + gsw*8),
        (AS3 void*)(Lbuf + rbase*64), 16, 0, 0);
    }
  };

  f32x4 acc[4][4] = {};
  const int ksteps = K>>6;

  stage(A, lda, m0, 0, Abuf[0]);
  stage(B, ldb, n0, 0, Bbuf[0]);
  asm volatile("s_waitcnt vmcnt(0)" ::: "memory");
  __syncthreads();

  for (int ks=0; ks<ksteps; ++ks){
    const int cb = ks&1;
    if (ks+1 < ksteps){
      stage(A, lda, m0, (ks+1)<<6, Abuf[cb^1]);
      stage(B, ldb, n0, (ks+1)<<6, Bbuf[cb^1]);
    }
    const u16* Al = Abuf[cb];
    const u16* Bl = Bbuf[cb];
    #pragma unroll
    for (int kk=0;kk<2;++kk){
      const int ko = kk*32 + (l>>4)*8;
      bf16x8 af[4], bfr[4];
      #pragma unroll
      for (int m=0;m<4;++m){
        const int row = wm*64+m*16+(l&15);
        af[m] = *(const bf16x8*)&Al[row*64 + (ko ^ ((row&7)<<3))];
      }
      #pragma unroll
      for (int n=0;n<4;++n){
        const int row = wn*64+n*16+(l&15);
        bfr[n] = *(const bf16x8*)&Bl[row*64 + (ko ^ ((row&7)<<3))];
      }
      #pragma unroll
      for (int m=0;m<4;++m)
        #pragma unroll
        for (int n=0;n<4;++n)
          acc[m][n] = __builtin_amdgcn_mfma_f32_16x16x32_bf16(af[m], bfr[n], acc[m][n], 0,0,0);
    }
    asm volatile("s_waitcnt vmcnt(0)" ::: "memory");
    __syncthreads();
  }

  float bv[4];
  #pragma unroll
  for (int n=0;n<4;++n) bv[n] = bias[n0 + wn*64 + n*16 + (l&15)];
  #pragma unroll
  for (int m=0;m<4;++m){
    const int rb = m0 + wm*64 + m*16 + (l>>4)*4;
    #pragma unroll
    for (int n=0;n<4;++n){
      const int col = n0 + wn*64 + n*16 + (l&15);
      #pragma unroll
      for (int r=0;r<4;++r){
        const int rr = rb + r;
        if (rr < Mstore) C[(size_t)rr*ldc + col] = f2bf(acc[m][n][r] + bv[n]);
      }
    }
  }
}

// ---------------- FUSED scan + output-GEMM (producer-consumer) ----------------
// EXACT R12 scan structure (best measured: 518 total) with ONE isolated change:
// gi prefetch deepened 2-ahead -> 3-AHEAD (4 LDS buffers) to hide the decoder-
// phase MALL latency under 248-consumer contention. vmcnt ledger re-derived:
// encoder keeps stage(s+2,s+3) -> vmcnt(6); decoder keeps stores(tt):8 +
// stage(tt+2,tt+3):6 -> vmcnt(14). Flag semantics unchanged.
// smem = max(scan 139776, gemm 98304) = 139776 (1 block/CU both branches).

__global__ __launch_bounds__(512,1) void fused_scan_gemm(
  const u16* Whhe, const u16* Whhd, const u16* Wihdc,
  const float* bhhe, const float* bhhd,
  const u16* enc_gi, const u16* dec_gi,
  u16* feat, u16* wout_b, const float* W_out,
  float* Cg, const float* b_out, u32* ctr)
{
  __shared__ __align__(16) char smem[139776];
  const int t = threadIdx.x;
  const int w = t>>6, l = t&63;

  if (blockIdx.x < 4){
    // ================= scan branch =================
    const int g = blockIdx.x;
    const int la = l&15, q = l>>4;
    const int brow0 = g*16;

    u16* hb   = (u16*)smem;               // [2][16][264]  (16896 B)
    u16* gib  = (u16*)(smem + 16896);     // [4][16][768]  (98304 B), LINEAR
    u16* ctxb = (u16*)(smem + 115200);    // [16][768]     (24576 B)

    bf16x8 Bf[48];

    auto loadW = [&](const u16* __restrict__ W){
      #pragma unroll
      for (int nt=0; nt<6; ++nt)
        #pragma unroll
        for (int kk=0; kk<8; ++kk)
          Bf[nt*8+kk] = *(const bf16x8*)&W[(size_t)(w*96 + nt*16 + la)*256 + kk*32 + q*8];
    };

    // bf16 gi stage: 24KB per step, 3 global_load_lds per thread, LINEAR
    auto stage = [&](const u16* __restrict__ gsrc, int step, u16* dstL){
      const u16* src = gsrc + (size_t)(step*64 + brow0)*768;
      #pragma unroll
      for (int i=0;i<3;++i){
        const int off = i*4096 + w*512;     // u16 units, wave-uniform
        __builtin_amdgcn_global_load_lds((const AS1 void*)(src + off + l*8),
                                         (AS3 void*)(dstL + off), 16, 0, 0);
      }
    };

    auto mm = [&](const u16* hsrc, f32x4* acc){
      #pragma unroll
      for (int kk=0; kk<8; ++kk){
        bf16x8 a = *(const bf16x8*)&hsrc[la*264 + kk*32 + q*8];
        #pragma unroll
        for (int nt=0; nt<6; ++nt)
          acc[nt] = __builtin_amdgcn_mfma_f32_16x16x32_bf16(a, Bf[nt*8+kk], acc[nt], 0,0,0);
      }
    };

    for (int i=t; i<2*16*264; i+=512) hb[i] = 0;
    loadW(Whhe);
    float bn[2];
    #pragma unroll
    for (int tl=0; tl<2; ++tl) bn[tl] = bhhe[w*96 + tl*16 + la + 64];
    stage(enc_gi, 0, gib);
    stage(enc_gi, 1, gib + 12288);
    stage(enc_gi, 2, gib + 2*12288);
    asm volatile("s_waitcnt vmcnt(0) lgkmcnt(0)" ::: "memory");
    __builtin_amdgcn_s_barrier();

    // ---- encoder: 50 steps, 3-ahead prefetch ----
    #pragma unroll 1
    for (int s=0; s<50; ++s){
      const int cur = s&1;
      const u16* gT = gib + (s&3)*12288;
      if (s+3 < 50) stage(enc_gi, s+3, gib + ((s+3)&3)*12288);
      f32x4 acc[6] = {};
      mm(hb + cur*4224, acc);
      #pragma unroll
      for (int tl=0; tl<2; ++tl){
        const int pb = w*96 + tl*16 + la;
        const int j  = w*32 + tl*16 + la;
        #pragma unroll
        for (int r=0;r<4;++r){
          const int b = q*4 + r;
          const float gir = bf2f(gT[b*768 + pb]);
          const float giz = bf2f(gT[b*768 + pb + 32]);
          const float gin = bf2f(gT[b*768 + pb + 64]);
          const float ho = bf2f(hb[cur*4224 + b*264 + j]);
          const float rg = fast_sig(gir + acc[tl][r]);
          const float zg = fast_sig(giz + acc[2+tl][r]);
          const float ng = fast_tanh(gin + rg*(acc[4+tl][r] + bn[tl]));
          hb[(cur^1)*4224 + b*264 + j] = f2bf((1.f-zg)*ng + zg*ho);
        }
      }
      if (s+3 < 50) asm volatile("s_waitcnt vmcnt(6) lgkmcnt(0)" ::: "memory");
      else          asm volatile("s_waitcnt vmcnt(0) lgkmcnt(0)" ::: "memory");
      __builtin_amdgcn_s_barrier();
    }
    // context in hb[0]

    // ---- stage decoder steps 0,1,2 (bufs 0..2 free after encoder) ----
    stage(dec_gi, 0, gib);
    stage(dec_gi, 1, gib + 12288);
    stage(dec_gi, 2, gib + 2*12288);

    // ---- ctx gate input (step-invariant) -> ctxb ----
    loadW(Wihdc);
    {
      f32x4 acc[6] = {};
      mm(hb, acc);
      #pragma unroll
      for (int nt=0; nt<6; ++nt)
        #pragma unroll
        for (int r=0;r<4;++r)
          ctxb[(q*4+r)*768 + w*96 + nt*16 + la] = f2bf(acc[nt][r]);
    }

    // ---- feat context columns [254,508): u32 device-scope (c2<127 guard) ----
    #pragma unroll 1
    for (int i=t; i<49*2048; i+=512){
      const int tt = i>>11, rem = i&2047, b = rem>>7, c2 = rem&127;
      if (c2 < 127){
        u32 v = *(const u32*)&hb[b*264 + c2*2];
        dev_store_u32((u32*)&feat[(size_t)(tt*64 + brow0 + b)*640 + 254 + c2*2], v);
      }
    }

    loadW(Whhd);
    #pragma unroll
    for (int tl=0; tl<2; ++tl) bn[tl] = bhhd[w*96 + tl*16 + la + 64];
    asm volatile("s_waitcnt vmcnt(0) lgkmcnt(0)" ::: "memory");
    __builtin_amdgcn_s_barrier();

    // ---- decoder: 49 steps; 3-ahead prefetch; flag = visible steps ----
    #pragma unroll 1
    for (int tt=0; tt<49; ++tt){
      const int cur = tt&1;
      const u16* gT = gib + (tt&3)*12288;
      if (tt+3 < 49) stage(dec_gi, tt+3, gib + ((tt+3)&3)*12288);
      f32x4 acc[6] = {};
      mm(hb + cur*4224, acc);
      #pragma unroll
      for (int tl=0; tl<2; ++tl){
        const int pb = w*96 + tl*16 + la;
        const int j  = w*32 + tl*16 + la;
        #pragma unroll
        for (int r=0;r<4;++r){
          const int b = q*4 + r;
          const float gir = bf2f(gT[b*768 + pb])      + bf2f(ctxb[b*768 + pb]);
          const float giz = bf2f(gT[b*768 + pb + 32]) + bf2f(ctxb[b*768 + pb + 32]);
          const float gin = bf2f(gT[b*768 + pb + 64]) + bf2f(ctxb[b*768 + pb + 64]);
          const float ho = bf2f(hb[cur*4224 + b*264 + j]);
          const float rg = fast_sig(gir + acc[tl][r]);
          const float zg = fast_sig(giz + acc[2+tl][r]);
          const float ng = fast_tanh(gin + rg*(acc[4+tl][r] + bn[tl]));
          const float h2 = (1.f-zg)*ng + zg*ho;
          const u16 hbv = f2bf(h2);
          hb[(cur^1)*4224 + b*264 + j] = hbv;
          if (j < 254) dev_store_u16(&feat[(size_t)(tt*64 + brow0 + b)*640 + j], hbv);
        }
      }
      // ledger: keep {stores(tt):8 + stage(tt+2):3 + stage(tt+3):3} = 14;
      // drains stage(tt+1) + stores(tt-1) -> flag tt safe to publish.
      if (tt+3 < 49) asm volatile("s_waitcnt vmcnt(14) lgkmcnt(0)" ::: "memory");
      else           asm volatile("s_waitcnt vmcnt(8) lgkmcnt(0)"  ::: "memory");
      __builtin_amdgcn_s_barrier();
      if (t==0) dev_store_u32(&ctr[g], (u32)tt);   // steps 0..tt-1 visible
    }
    asm volatile("s_waitcnt vmcnt(0)" ::: "memory");
    __syncthreads();
    if (t==0) dev_store_u32(&ctr[g], 49u);         // all steps visible
    return;
  }

  // ================= gemm branch =================
  const int bg = blockIdx.x - 4;
  const int wm = w>>2, wn = w&3;
  const int la = l&15, q = l>>4;
  const int lr = l>>3, lg = l&7;

  u16* AL = (u16*)smem;             // [2][128*64]  (32768 B)
  u16* BL = (u16*)(smem + 32768);   // [2][256*64]  (65536 B)

  // (a) convert my W_out slice during the encoder window (DEVICE-SCOPE).
  if (bg < 125){
    const int n0c = bg<<8;
    #pragma unroll 1
    for (int i=t; i<256*80; i+=512){
      const int r = i/80, c8 = (i - r*80)<<3;
      u16 o[8];
      #pragma unroll
      for (int jj=0;jj<8;++jj){
        const int c = c8 + jj;
        o[jj] = (c < 636) ? f2bf(W_out[(size_t)(n0c+r)*636 + c]) : (u16)0;
      }
      u32* dst = (u32*)&wout_b[(size_t)(n0c+r)*640 + c8];
      const u32* sv = (const u32*)o;
      #pragma unroll
      for (int jj=0;jj<4;++jj) dev_store_u32(&dst[jj], sv[jj]);
    }
    asm volatile("s_waitcnt vmcnt(0)" ::: "memory");
    __syncthreads();
    if (t==0) dev_store_u32(&ctr[32 + bg], 1u);
  }

  // (b) consume tiles: relaxed polls, staggered sleep
  const int nsleep = 1 + (bg&3);
  #pragma unroll 1
  for (int tau = bg; tau < 3125; tau += 248){
    const int mt = tau/125, nt = tau - mt*125;
    const int m0 = mt<<7, n0 = nt<<8;
    const u32 need = (u32)((2*mt+2 < 49) ? (2*mt+2) : 49);

    if (w==0){
      int cnt = 0;
      while (true){
        u32 v  = (l<4) ? __hip_atomic_load(&ctr[l], __ATOMIC_RELAXED, __HIP_MEMORY_SCOPE_AGENT) : 0xFFFFFFFFu;
        u32 wf = (l==4) ? __hip_atomic_load(&ctr[32 + nt], __ATOMIC_RELAXED, __HIP_MEMORY_SCOPE_AGENT) : 1u;
        if (__all((int)((v >= need) && (wf != 0u)))) break;
        for (int z=0; z<nsleep; ++z) __builtin_amdgcn_s_sleep(16);
        if (++cnt > (1<<22)) break;   // safety
      }
    }
    __syncthreads();

    auto stageA = [&](int k0, int buf){
      #pragma unroll
      for (int i=0;i<2;++i){
        const int rbase = i*64 + w*8;
        const int r = rbase + lr;
        __builtin_amdgcn_global_load_lds(
          (const AS1 void*)(feat + (size_t)(m0+r)*640 + k0 + ((lg^lr)<<3)),
          (AS3 void*)(AL + buf*8192 + rbase*64), 16, 0, 0);
      }
    };
    auto stageB = [&](int k0, int buf){
      #pragma unroll
      for (int i=0;i<4;++i){
        const int rbase = i*64 + w*8;
        const int r = rbase + lr;
        __builtin_amdgcn_global_load_lds(
          (const AS1 void*)(wout_b + (size_t)(n0+r)*640 + k0 + ((lg^lr)<<3)),
          (AS3 void*)(BL + buf*16384 + rbase*64), 16, 0, 0);
      }
    };

    f32x4 acc[4][4] = {};
    stageA(0,0); stageB(0,0);
    asm volatile("s_waitcnt vmcnt(0)" ::: "memory");
    __syncthreads();

    #pragma unroll 1
    for (int ks=0; ks<10; ++ks){
      const int cb = ks&1;
      if (ks < 9){ stageA((ks+1)<<6, cb^1); stageB((ks+1)<<6, cb^1); }
      const u16* Alp = AL + cb*8192;
      const u16* Blp = BL + cb*16384;
      #pragma unroll
      for (int kk=0;kk<2;++kk){
        const int ko = kk*32 + q*8;
        bf16x8 af[4], bfr[4];
        #pragma unroll
        for (int m=0;m<4;++m){
          const int row = wm*64 + m*16 + la;
          af[m] = *(const bf16x8*)&Alp[row*64 + (ko ^ ((row&7)<<3))];
        }
        #pragma unroll
        for (int n=0;n<4;++n){
          const int row = wn*64 + n*16 + la;
          bfr[n] = *(const bf16x8*)&Blp[row*64 + (ko ^ ((row&7)<<3))];
        }
        #pragma unroll
        for (int m=0;m<4;++m)
          #pragma unroll
          for (int n=0;n<4;++n)
            acc[m][n] = __builtin_amdgcn_mfma_f32_16x16x32_bf16(af[m], bfr[n], acc[m][n], 0,0,0);
      }
      asm volatile("s_waitcnt vmcnt(0)" ::: "memory");
      __syncthreads();
    }

    float bv[4];
    #pragma unroll
    for (int n=0;n<4;++n) bv[n] = b_out[n0 + wn*64 + n*16 + la];
    #pragma unroll
    for (int m=0;m<4;++m){
      const int rb = m0 + wm*64 + m*16 + q*4;
      #pragma unroll
      for (int n=0;n<4;++n){
        const int col = n0 + wn*64 + n*16 + la;
        #pragma unroll
        for (int r=0;r<4;++r){
          const int rr = rb + r;
          if (rr < 3136)
            __builtin_nontemporal_store(acc[m][n][r] + bv[n], &Cg[(size_t)rr*32000 + col]);
        }
      }
    }
  }
}

// ---------------- launch ----------------

extern "C" void kernel_launch(void* const* d_in, const int* in_sizes, int n_in,
                              void* d_out, int out_size, void* d_ws, size_t ws_size,
                              hipStream_t stream) {
  const int*   src     = (const int*)d_in[0];
  const int*   trg     = (const int*)d_in[1];
  const float* emb_enc = (const float*)d_in[2];
  const float* W_ih_e  = (const float*)d_in[3];
  const float* W_hh_e  = (const float*)d_in[4];
  const float* b_ih_e  = (const float*)d_in[5];
  const float* b_hh_e  = (const float*)d_in[6];
  const float* emb_dec = (const float*)d_in[7];
  const float* W_ih_d  = (const float*)d_in[8];
  const float* W_hh_d  = (const float*)d_in[9];
  const float* b_ih_d  = (const float*)d_in[10];
  const float* b_hh_d  = (const float*)d_in[11];
  const float* W_out   = (const float*)d_in[12];
  const float* b_out   = (const float*)d_in[13];
  float* out = (float*)d_out;

  char* basep = (char*)d_ws;
  size_t off = 0;
  auto take = [&](size_t b)->char*{ char* p = basep + off; off = (off + b + 255) & ~(size_t)255; return p; };
  u16* feat    = (u16*)take(4096000);   // [3200][640] bf16
  u32* ctr     = (u32*)take(4096);      // flags: [0..3] scan, [32+nt] wout
  u16* wout_b  = (u16*)take(40960000);  // [32000][640]
  u16* wihe_b  = (u16*)take(196608);    // [768][128] permuted
  u16* wihde_b = (u16*)take(196608);    // [768][128] permuted
  u16* wihdc_b = (u16*)take(393216);    // [768][256] permuted
  u16* whhe_b  = (u16*)take(393216);    // [768][256] permuted
  u16* whhd_b  = (u16*)take(393216);    // [768][256] permuted
  u16* encx_b  = (u16*)take(819200);    // [3200][128]
  u16* dece_b  = (u16*)take(819200);    // [3200][128]
  u16* enc_gi  = (u16*)take(4915200);   // [3200][768] bf16 (permuted cols)
  u16* dec_gi  = (u16*)take(4915200);   // [3200][768] bf16 (permuted cols)
  float* bihe_p = (float*)take(3072);
  float* bihd_p = (float*)take(3072);
  float* bhhe_p = (float*)take(3072);
  float* bhhd_p = (float*)take(3072);
  (void)in_sizes; (void)n_in; (void)out_size; (void)ws_size;

  // zero flags and output row 0
  zero_bytes<<<1, 256, 0, stream>>>((uint4*)ctr, (size_t)(4096/16));
  zero_bytes<<<2000, 256, 0, stream>>>((uint4*)out, (size_t)(8192000/16));

  // permuted gate-weight packs
  pad_convert_g<<<384, 256, 0, stream>>>(W_ih_e, 128,   0, 128, wihe_b, 128);
  pad_convert_g<<<384, 256, 0, stream>>>(W_ih_d, 382,   0, 128, wihde_b, 128);
  pad_convert_g<<<768, 256, 0, stream>>>(W_ih_d, 382, 128, 254, wihdc_b, 256);
  pad_convert_g<<<768, 256, 0, stream>>>(W_hh_e, 254,   0, 254, whhe_b, 256);
  pad_convert_g<<<768, 256, 0, stream>>>(W_hh_d, 254,   0, 254, whhd_b, 256);

  pad_bias_comb<<<3, 256, 0, stream>>>(b_ih_e, b_hh_e, bihe_p);
  pad_bias_comb<<<3, 256, 0, stream>>>(b_ih_d, b_hh_d, bihd_p);
  pad_bias_g<<<3, 256, 0, stream>>>(b_hh_e, bhhe_p);
  pad_bias_g<<<3, 256, 0, stream>>>(b_hh_d, bhhd_p);

  gather_enc<<<1600, 256, 0, stream>>>(src, emb_enc, encx_b);
  gather_dec<<<1600, 256, 0, stream>>>(trg, emb_dec, dece_b, feat);

  // gi = bf16( x @ W_ih^T + (b_ih + b_hh_rz) )  (M=3200, N=768 permuted, K=128)
  gemm_bt16<<<25*6, 256, 0, stream>>>(encx_b, 128, wihe_b, 128, enc_gi, (long long)768, bihe_p, 128, 25, 3200);
  gemm_bt16<<<25*6, 256, 0, stream>>>(dece_b, 128, wihde_b, 128, dec_gi, (long long)768, bihd_p, 128, 25, 3200);

  // fused: scan (blocks 0-3) + W_out convert + output GEMM (blocks 4-251)
  fused_scan_gemm<<<252, 512, 0, stream>>>(whhe_b, whhd_b, wihdc_b, bhhe_p, bhhd_p,
                                           enc_gi, dec_gi, feat, wout_b, W_out,
                                           out + (size_t)64*32000, b_out, ctr);
}